// Round 2
// baseline (1333.075 us; speedup 1.0000x reference)
//
#include <hip/hip_runtime.h>
#include <hip/hip_bf16.h>
#include <stdint.h>

#define B_  4
#define T_  2048
#define C_  2048
#define H_  32
#define S_  64
#define M_  (B_ * T_)     // 8192 rows
#define C4_ (4 * C_)      // 8192
#define LN_EPS 1e-5f
#define NCH 16            // scan chunks
#define CLEN 128          // chunk length (NCH*CLEN == T_)
#define NCHAN (B_ * C_)   // 8192 scan channels

typedef unsigned short u16;
typedef __attribute__((ext_vector_type(8))) short short8;
typedef __attribute__((ext_vector_type(4))) float f32x4;

__device__ __forceinline__ u16 f2bf(float f) {
  uint32_t u = __float_as_uint(f);
  u = (u + 0x7FFFu + ((u >> 16) & 1u)) >> 16;
  return (u16)u;
}
__device__ __forceinline__ float bf2f(u16 u) {
  return __uint_as_float(((uint32_t)u) << 16);
}

__device__ __forceinline__ void gload_lds16(const void* g, void* l) {
  __builtin_amdgcn_global_load_lds(
      (const __attribute__((address_space(1))) uint32_t*)g,
      (__attribute__((address_space(3))) uint32_t*)l, 16, 0, 0);
}

// ---- transpose + cast: f32 in[R][Cn] (leading dim ld) -> bf16 out[Cn][R] ----
__global__ __launch_bounds__(256) void k_transpose_cast(
    const float* __restrict__ in, u16* __restrict__ out, int ld, int R, int Cn) {
  __shared__ float tile[32][33];
  const int tx = threadIdx.x & 31, ty = threadIdx.x >> 5; // ty 0..7
  const int c0 = blockIdx.x * 32, r0 = blockIdx.y * 32;
#pragma unroll
  for (int i = 0; i < 4; ++i) {
    int r = ty + i * 8;
    tile[r][tx] = in[(size_t)(r0 + r) * ld + (c0 + tx)];
  }
  __syncthreads();
#pragma unroll
  for (int i = 0; i < 4; ++i) {
    int cc = ty + i * 8;
    out[(size_t)(c0 + cc) * R + (r0 + tx)] = f2bf(tile[tx][cc]);
  }
}

// ---------------- LayerNorm f32 -> bf16, one block per row ----------------
__global__ __launch_bounds__(256) void k_layernorm_bf16(
    const float* __restrict__ x, const float* __restrict__ w,
    const float* __restrict__ bias, u16* __restrict__ out) {
  const int row = blockIdx.x;
  const int t = threadIdx.x;
  const float* xr = x + (size_t)row * C_;
  float4 a = ((const float4*)xr)[2 * t];
  float4 b = ((const float4*)xr)[2 * t + 1];
  float s = a.x + a.y + a.z + a.w + b.x + b.y + b.z + b.w;
  float q = a.x * a.x + a.y * a.y + a.z * a.z + a.w * a.w +
            b.x * b.x + b.y * b.y + b.z * b.z + b.w * b.w;
#pragma unroll
  for (int off = 32; off > 0; off >>= 1) {
    s += __shfl_down(s, off);
    q += __shfl_down(q, off);
  }
  __shared__ float rs[8];
  const int wv = t >> 6;
  if ((t & 63) == 0) { rs[wv] = s; rs[4 + wv] = q; }
  __syncthreads();
  s = rs[0] + rs[1] + rs[2] + rs[3];
  q = rs[4] + rs[5] + rs[6] + rs[7];
  const float mean = s * (1.0f / C_);
  const float rstd = rsqrtf(q * (1.0f / C_) - mean * mean + LN_EPS);
  float4 w0 = ((const float4*)w)[2 * t], w1 = ((const float4*)w)[2 * t + 1];
  float4 b0 = ((const float4*)bias)[2 * t], b1 = ((const float4*)bias)[2 * t + 1];
  uint4 pk;
  pk.x = (uint32_t)f2bf((a.x - mean) * rstd * w0.x + b0.x) |
         ((uint32_t)f2bf((a.y - mean) * rstd * w0.y + b0.y) << 16);
  pk.y = (uint32_t)f2bf((a.z - mean) * rstd * w0.z + b0.z) |
         ((uint32_t)f2bf((a.w - mean) * rstd * w0.w + b0.w) << 16);
  pk.z = (uint32_t)f2bf((b.x - mean) * rstd * w1.x + b1.x) |
         ((uint32_t)f2bf((b.y - mean) * rstd * w1.y + b1.y) << 16);
  pk.w = (uint32_t)f2bf((b.z - mean) * rstd * w1.z + b1.z) |
         ((uint32_t)f2bf((b.w - mean) * rstd * w1.w + b1.w) << 16);
  ((uint4*)(out + (size_t)row * C_))[t] = pk;
}

// ---------------- GEMM: A[M,K] bf16 row-major, Bt[N,K] bf16 row-major ----------------
// 128x128 tile, BK=64, 4 waves (2x2), 16x16x32 bf16 MFMA.
// LDS XOR-swizzle (granule ^= row&7) applied on the GLOBAL source of
// global_load_lds (linear LDS dest) and on the ds_read address. (T2 / m201)
// EPI: 0 f32 store | 1 f32 Res+v | 2 bf16 | 3 bf16 relu^2 | 4 f32 Out+=v
template <int EPI>
__global__ __launch_bounds__(256) void k_gemm_bt(
    const u16* __restrict__ A, const u16* __restrict__ Bt,
    void* __restrict__ Out, const float* __restrict__ Res,
    int M, int N, int K) {
  __shared__ u16 As[128 * 64];
  __shared__ u16 Bs[128 * 64];
  const int tid = threadIdx.x;
  const int wv = tid >> 6, ln = tid & 63;
  const int wm = wv >> 1, wn = wv & 1;
  const int bm0 = blockIdx.y * 128, bn0 = blockIdx.x * 128;

  f32x4 acc[4][4];
#pragma unroll
  for (int m = 0; m < 4; ++m)
#pragma unroll
    for (int n = 0; n < 4; ++n) acc[m][n] = (f32x4)0.0f;

  const int g_l = ln & 7;               // granule slot this lane fills
  const int rsub = wv * 8 + (ln >> 3);  // row-within-32-group

  for (int k0 = 0; k0 < K; k0 += 64) {
#pragma unroll
    for (int i = 0; i < 4; ++i) {
      const int row = i * 32 + rsub;
      const int gsrc = g_l ^ (row & 7);
      gload_lds16(A + (size_t)(bm0 + row) * K + k0 + gsrc * 8,
                  ((char*)As) + i * 4096 + wv * 1024);
    }
#pragma unroll
    for (int i = 0; i < 4; ++i) {
      const int row = i * 32 + rsub;
      const int gsrc = g_l ^ (row & 7);
      gload_lds16(Bt + (size_t)(bn0 + row) * K + k0 + gsrc * 8,
                  ((char*)Bs) + i * 4096 + wv * 1024);
    }
    __syncthreads();
#pragma unroll
    for (int kk = 0; kk < 2; ++kk) {
      short8 af[4], bfr[4];
#pragma unroll
      for (int m = 0; m < 4; ++m) {
        const int row = wm * 64 + m * 16 + (ln & 15);
        const int g = (kk * 4 + (ln >> 4)) ^ (row & 7);
        af[m] = *(const short8*)&As[row * 64 + g * 8];
      }
#pragma unroll
      for (int n = 0; n < 4; ++n) {
        const int row = wn * 64 + n * 16 + (ln & 15);
        const int g = (kk * 4 + (ln >> 4)) ^ (row & 7);
        bfr[n] = *(const short8*)&Bs[row * 64 + g * 8];
      }
#pragma unroll
      for (int m = 0; m < 4; ++m)
#pragma unroll
        for (int n = 0; n < 4; ++n)
          acc[m][n] = __builtin_amdgcn_mfma_f32_16x16x32_bf16(
              af[m], bfr[n], acc[m][n], 0, 0, 0);
    }
    __syncthreads();
  }

  // epilogue: D row = (ln>>4)*4 + i, col = ln&15  (verified m89/m91)
#pragma unroll
  for (int m = 0; m < 4; ++m) {
    const int r_base = bm0 + wm * 64 + m * 16 + (ln >> 4) * 4;
#pragma unroll
    for (int n = 0; n < 4; ++n) {
      const int cidx = bn0 + wn * 64 + n * 16 + (ln & 15);
#pragma unroll
      for (int i = 0; i < 4; ++i) {
        const size_t off = (size_t)(r_base + i) * N + cidx;
        const float v = acc[m][n][i];
        if constexpr (EPI == 0) {
          ((float*)Out)[off] = v;
        } else if constexpr (EPI == 1) {
          ((float*)Out)[off] = Res[off] + v;
        } else if constexpr (EPI == 2) {
          ((u16*)Out)[off] = f2bf(v);
        } else if constexpr (EPI == 3) {
          const float tpos = v > 0.0f ? v : 0.0f;
          ((u16*)Out)[off] = f2bf(tpos * tpos);
        } else {
          ((float*)Out)[off] += v;
        }
      }
    }
  }
}

// ---------------- wkv scan, 3 passes (chunked exp-decay cumsum) ----------------
__global__ __launch_bounds__(256) void k_scan_a(
    const float* __restrict__ kk, const u16* __restrict__ vv,
    const float* __restrict__ td, float* __restrict__ Sloc) {
  const int g = blockIdx.x * 256 + threadIdx.x;   // channel 0..8191
  const int j = blockIdx.y;                       // chunk
  const int ch = g & (C_ - 1);
  const float d = __expf(-__expf(td[ch]));
  const size_t base = ((size_t)(g >> 11) * T_ + (size_t)j * CLEN) * C_ + ch;
  float s = 0.0f;
#pragma unroll 4
  for (int t = 0; t < CLEN; ++t) {
    const size_t idx = base + (size_t)t * C_;
    s = d * s + __expf(kk[idx]) * bf2f(vv[idx]);
  }
  Sloc[(size_t)j * NCHAN + g] = s;
}

__global__ __launch_bounds__(256) void k_scan_b(
    const float* __restrict__ td, const float* __restrict__ Sloc,
    float* __restrict__ carry) {
  const int g = blockIdx.x * 256 + threadIdx.x;
  const int ch = g & (C_ - 1);
  const float dL = __expf(-__expf(td[ch]) * (float)CLEN);
  float s = 0.0f;
#pragma unroll
  for (int j = 0; j < NCH; ++j) {
    carry[(size_t)j * NCHAN + g] = s;
    s = dL * s + Sloc[(size_t)j * NCHAN + g];
  }
}

// pass C: replay with carry, add t=0 bonus, gate with sigmoid(r);
// rwkv may alias rr (in-place): rr[idx] is read before rwkv[idx] is written.
__global__ __launch_bounds__(256) void k_scan_c(
    const float* __restrict__ kk, const u16* __restrict__ vv,
    const u16* __restrict__ rr, const float* __restrict__ td,
    const float* __restrict__ tf, const float* __restrict__ carry,
    u16* __restrict__ rwkv) {
  const int g = blockIdx.x * 256 + threadIdx.x;
  const int j = blockIdx.y;
  const int ch = g & (C_ - 1);
  const float d = __expf(-__expf(td[ch]));
  const float bonus = __expf(tf[ch]);
  const size_t base = ((size_t)(g >> 11) * T_ + (size_t)j * CLEN) * C_ + ch;
  float s = carry[(size_t)j * NCHAN + g];
#pragma unroll 2
  for (int t = 0; t < CLEN; ++t) {
    const size_t idx = base + (size_t)t * C_;
    const float vval = bf2f(vv[idx]);
    s = d * s + __expf(kk[idx]) * vval;
    float wkv = s;
    if (j == 0 && t == 0) wkv += bonus * vval;  // t=0 bonus, output only
    const float rv = bf2f(rr[idx]);
    const float sg = 1.0f / (1.0f + __expf(-rv));
    rwkv[idx] = f2bf(sg * wkv);
  }
}

// ---------------- host launch ----------------
extern "C" void kernel_launch(void* const* d_in, const int* in_sizes, int n_in,
                              void* d_out, int out_size, void* d_ws, size_t ws_size,
                              hipStream_t stream) {
  const float* x    = (const float*)d_in[0];
  const float* td   = (const float*)d_in[1];
  const float* tf   = (const float*)d_in[2];
  const float* Wk   = (const float*)d_in[3];
  const float* Wv   = (const float*)d_in[4];
  const float* Wr   = (const float*)d_in[5];
  const float* Wo   = (const float*)d_in[6];
  const float* Wfk  = (const float*)d_in[7];
  const float* Wfv  = (const float*)d_in[8];
  const float* ln1w = (const float*)d_in[9];
  const float* ln1b = (const float*)d_in[10];
  const float* ln2w = (const float*)d_in[11];
  const float* ln2b = (const float*)d_in[12];
  float* out = (float*)d_out;

  // lean workspace arena (~169 MB), buffers reused aggressively
  char* p = (char*)d_ws;
  auto alloc = [&](size_t bytes) {
    char* r = p;
    p += (bytes + 255) & ~(size_t)255;
    return r;
  };
  u16*   wbuf = (u16*)alloc((size_t)C_ * C_ * 2);    //  8 MB: every transposed weight, serially
  u16*   xl   = (u16*)alloc((size_t)M_ * C_ * 2);    // 32 MB: LN1 out; later FFN hidden chunk
  float* kbuf = (float*)alloc((size_t)M_ * C_ * 4);  // 64 MB: k f32 (dead after scan)
  u16*   vbuf = (u16*)alloc((size_t)M_ * C_ * 2);    // 32 MB: v; later xl2
  u16*   rbuf = (u16*)alloc((size_t)M_ * C_ * 2);    // 32 MB: r; rwkv written in place
  float* Sloc = (float*)alloc((size_t)NCH * NCHAN * 4);
  float* carry = (float*)alloc((size_t)NCH * NCHAN * 4);
  u16* hchunk = xl;   // alias: xl dead after r-projection
  u16* rwkv = rbuf;   // alias: in-place gate (read-before-write per element)

  const dim3 tgrid(C_ / 32, C_ / 32);   // 2048x2048 transpose
  const dim3 ggrid(C_ / 128, M_ / 128); // N=2048 GEMM grid

  // 1) LN1
  k_layernorm_bf16<<<M_, 256, 0, stream>>>(x, ln1w, ln1b, xl);

  // 2) projections (transpose each weight into wbuf just-in-time; stream-serial)
  k_transpose_cast<<<tgrid, 256, 0, stream>>>(Wk, wbuf, C_, C_, C_);
  k_gemm_bt<0><<<ggrid, 256, 0, stream>>>(xl, wbuf, kbuf, nullptr, M_, C_, C_);
  k_transpose_cast<<<tgrid, 256, 0, stream>>>(Wv, wbuf, C_, C_, C_);
  k_gemm_bt<2><<<ggrid, 256, 0, stream>>>(xl, wbuf, vbuf, nullptr, M_, C_, C_);
  k_transpose_cast<<<tgrid, 256, 0, stream>>>(Wr, wbuf, C_, C_, C_);
  k_gemm_bt<2><<<ggrid, 256, 0, stream>>>(xl, wbuf, rbuf, nullptr, M_, C_, C_);

  // 3) wkv chunked scan + sigmoid gate (rwkv in place of r)
  k_scan_a<<<dim3(NCHAN / 256, NCH), 256, 0, stream>>>(kbuf, vbuf, td, Sloc);
  k_scan_b<<<dim3(NCHAN / 256), 256, 0, stream>>>(td, Sloc, carry);
  k_scan_c<<<dim3(NCHAN / 256, NCH), 256, 0, stream>>>(kbuf, vbuf, rbuf, td, tf, carry, rwkv);

  // 4) x2 = x + rwkv @ Wo  -> straight into d_out
  k_transpose_cast<<<tgrid, 256, 0, stream>>>(Wo, wbuf, C_, C_, C_);
  k_gemm_bt<1><<<ggrid, 256, 0, stream>>>(rwkv, wbuf, out, x, M_, C_, C_);

  // 5) LN2 (xl2 into vbuf)
  u16* xl2 = vbuf;
  k_layernorm_bf16<<<M_, 256, 0, stream>>>(out, ln2w, ln2b, xl2);

  // 6) FFN chunked over the 4C dimension: out += relu(xl2@Wfk_c)^2 @ Wfv_c
  for (int c = 0; c < 4; ++c) {
    // WfkT chunk: transpose of Wfk[:, c*2048 : (c+1)*2048]  (ld = 4C)
    k_transpose_cast<<<tgrid, 256, 0, stream>>>(Wfk + (size_t)c * C_, wbuf, C4_, C_, C_);
    k_gemm_bt<3><<<ggrid, 256, 0, stream>>>(xl2, wbuf, hchunk, nullptr, M_, C_, C_);
    // WfvT chunk: transpose of Wfv[c*2048 : (c+1)*2048, :]  (ld = C)
    k_transpose_cast<<<tgrid, 256, 0, stream>>>(Wfv + (size_t)c * C_ * C_, wbuf, C_, C_, C_);
    k_gemm_bt<4><<<ggrid, 256, 0, stream>>>(hchunk, wbuf, out, nullptr, M_, C_, C_);
  }
}

// Round 3
// 1150.676 us; speedup vs baseline: 1.1585x; 1.1585x over previous
//
#include <hip/hip_runtime.h>
#include <hip/hip_bf16.h>
#include <stdint.h>

#define B_  4
#define T_  2048
#define C_  2048
#define H_  32
#define S_  64
#define M_  (B_ * T_)     // 8192 rows
#define C4_ (4 * C_)      // 8192
#define LN_EPS 1e-5f
#define NCH 16            // scan chunks
#define CLEN 128          // chunk length (NCH*CLEN == T_)
#define NCHAN (B_ * C_)   // 8192 scan channels

typedef unsigned short u16;
typedef __attribute__((ext_vector_type(8))) short short8;
typedef __attribute__((ext_vector_type(4))) float f32x4;

__device__ __forceinline__ u16 f2bf(float f) {
  uint32_t u = __float_as_uint(f);
  u = (u + 0x7FFFu + ((u >> 16) & 1u)) >> 16;
  return (u16)u;
}
__device__ __forceinline__ float bf2f(u16 u) {
  return __uint_as_float(((uint32_t)u) << 16);
}

__device__ __forceinline__ void gload_lds16(const void* g, void* l) {
  __builtin_amdgcn_global_load_lds(
      (const __attribute__((address_space(1))) uint32_t*)g,
      (__attribute__((address_space(3))) uint32_t*)l, 16, 0, 0);
}

// ---- transpose + cast: f32 in[R][Cn] (leading dim ld) -> bf16 out[Cn][R] ----
__global__ __launch_bounds__(256) void k_transpose_cast(
    const float* __restrict__ in, u16* __restrict__ out, int ld, int R, int Cn) {
  __shared__ float tile[32][33];
  const int tx = threadIdx.x & 31, ty = threadIdx.x >> 5; // ty 0..7
  const int c0 = blockIdx.x * 32, r0 = blockIdx.y * 32;
#pragma unroll
  for (int i = 0; i < 4; ++i) {
    int r = ty + i * 8;
    tile[r][tx] = in[(size_t)(r0 + r) * ld + (c0 + tx)];
  }
  __syncthreads();
#pragma unroll
  for (int i = 0; i < 4; ++i) {
    int cc = ty + i * 8;
    out[(size_t)(c0 + cc) * R + (r0 + tx)] = f2bf(tile[tx][cc]);
  }
}

// ---------------- LayerNorm f32 -> bf16, one block per row ----------------
__global__ __launch_bounds__(256) void k_layernorm_bf16(
    const float* __restrict__ x, const float* __restrict__ w,
    const float* __restrict__ bias, u16* __restrict__ out) {
  const int row = blockIdx.x;
  const int t = threadIdx.x;
  const float* xr = x + (size_t)row * C_;
  float4 a = ((const float4*)xr)[2 * t];
  float4 b = ((const float4*)xr)[2 * t + 1];
  float s = a.x + a.y + a.z + a.w + b.x + b.y + b.z + b.w;
  float q = a.x * a.x + a.y * a.y + a.z * a.z + a.w * a.w +
            b.x * b.x + b.y * b.y + b.z * b.z + b.w * b.w;
#pragma unroll
  for (int off = 32; off > 0; off >>= 1) {
    s += __shfl_down(s, off);
    q += __shfl_down(q, off);
  }
  __shared__ float rs[8];
  const int wv = t >> 6;
  if ((t & 63) == 0) { rs[wv] = s; rs[4 + wv] = q; }
  __syncthreads();
  s = rs[0] + rs[1] + rs[2] + rs[3];
  q = rs[4] + rs[5] + rs[6] + rs[7];
  const float mean = s * (1.0f / C_);
  const float rstd = rsqrtf(q * (1.0f / C_) - mean * mean + LN_EPS);
  float4 w0 = ((const float4*)w)[2 * t], w1 = ((const float4*)w)[2 * t + 1];
  float4 b0 = ((const float4*)bias)[2 * t], b1 = ((const float4*)bias)[2 * t + 1];
  uint4 pk;
  pk.x = (uint32_t)f2bf((a.x - mean) * rstd * w0.x + b0.x) |
         ((uint32_t)f2bf((a.y - mean) * rstd * w0.y + b0.y) << 16);
  pk.y = (uint32_t)f2bf((a.z - mean) * rstd * w0.z + b0.z) |
         ((uint32_t)f2bf((a.w - mean) * rstd * w0.w + b0.w) << 16);
  pk.z = (uint32_t)f2bf((b.x - mean) * rstd * w1.x + b1.x) |
         ((uint32_t)f2bf((b.y - mean) * rstd * w1.y + b1.y) << 16);
  pk.w = (uint32_t)f2bf((b.z - mean) * rstd * w1.z + b1.z) |
         ((uint32_t)f2bf((b.w - mean) * rstd * w1.w + b1.w) << 16);
  ((uint4*)(out + (size_t)row * C_))[t] = pk;
}

// ============ GEMM 256x256 tile, BK=64, 8 waves, 4-phase counted-vmcnt ============
// A[M,K] bf16 row-major, Bt[N,K] bf16 row-major, C = A*Bt^T.
// LDS per matrix: [dbuf 2][K-half 2][256 rows][32 cols] bf16 (16 KB per half-tile).
// Stage unit = one K-half-tile = 2 global_load_lds (16B) per thread.
// Phases P0..P3 per K-tile: (kk,mh) = (0,0),(0,1),(1,0),(1,1).
//   P0/P1 consume K-half 0; P2/P3 consume K-half 1  ->  the boundary waits only
//   need the OLDEST 4 loads: s_waitcnt vmcnt(4) at end of P1 and P3 (never 0
//   in steady state; T4).
// Swizzle: physical granule slot p of row holds data granule p ^ ((row>>1)&3);
//   applied on the global source (linear LDS dest, m104/m173) and on ds_read.
//   16-lane frag read -> 8 lanes per 4-bank group, uniform: conflict-free.
// EPI: 0 f32 store | 1 f32 Res+v | 2 bf16 | 3 bf16 relu^2 | 4 f32 Out+=v
__device__ __forceinline__ void stage_half(
    const u16* __restrict__ G, int ldK, int row0, int kcol0,
    u16* lds_half, int tid) {
#pragma unroll
  for (int i = 0; i < 2; ++i) {
    const int slot = i * 512 + tid;
    const int row = slot >> 2;
    const int gs = slot & 3;
    const int gsrc = gs ^ ((row >> 1) & 3);
    gload_lds16(G + (size_t)(row0 + row) * ldK + kcol0 + gsrc * 8,
                ((char*)lds_half) + i * 8192 + (tid >> 6) * 1024);
  }
}

__device__ __forceinline__ short8 frag(const u16* half_base, int row, int g0) {
  const int g = g0 ^ ((row >> 1) & 3);
  return *(const short8*)(half_base + row * 32 + g * 8);
}

template <int EPI>
__global__ __launch_bounds__(512, 2) void k_gemm8(
    const u16* __restrict__ A, const u16* __restrict__ Bt,
    void* __restrict__ Out, const float* __restrict__ Res,
    int M, int N, int K) {
  __shared__ u16 As[2][2][256 * 32];   // 64 KB
  __shared__ u16 Bs[2][2][256 * 32];   // 64 KB
  const int tid = threadIdx.x;
  const int wv = tid >> 6, ln = tid & 63;
  const int wm = wv >> 2, wn = wv & 3;          // 2 x 4 wave grid
  const int l15 = ln & 15, g0 = ln >> 4;
  const int bm0 = blockIdx.y * 256, bn0 = blockIdx.x * 256;
  const int NT = K >> 6;

  f32x4 acc[8][4];
#pragma unroll
  for (int m = 0; m < 8; ++m)
#pragma unroll
    for (int n = 0; n < 4; ++n) acc[m][n] = (f32x4)0.0f;

  // prologue: stage tile 0 fully (A-K0, B-K0, A-K1, B-K1) = 8 loads/thread
  stage_half(A, K, bm0, 0, &As[0][0][0], tid);
  stage_half(Bt, K, bn0, 0, &Bs[0][0][0], tid);
  stage_half(A, K, bm0, 32, &As[0][1][0], tid);
  stage_half(Bt, K, bn0, 32, &Bs[0][1][0], tid);
  asm volatile("s_waitcnt vmcnt(4)" ::: "memory");   // K0 halves landed
  __builtin_amdgcn_s_barrier();

  for (int t = 0; t < NT; ++t) {
    const int c = t & 1, nb = c ^ 1;
    const int kn = (t + 1) << 6;
    const bool stage_on = (t + 1 < NT);
    const bool lastt = (t + 1 == NT);
    short8 bfr[4], af[4];

    // ---------- P0: kk=0, m 0..3; stage t+1 A-K0 ----------
#pragma unroll
    for (int n = 0; n < 4; ++n)
      bfr[n] = frag(&Bs[c][0][0], wn * 64 + n * 16 + l15, g0);
#pragma unroll
    for (int m = 0; m < 4; ++m)
      af[m] = frag(&As[c][0][0], wm * 128 + m * 16 + l15, g0);
    if (stage_on) stage_half(A, K, bm0, kn, &As[nb][0][0], tid);
    __builtin_amdgcn_s_barrier();
    asm volatile("s_waitcnt lgkmcnt(0)" ::: "memory");
    __builtin_amdgcn_sched_barrier(0);
    __builtin_amdgcn_s_setprio(1);
#pragma unroll
    for (int m = 0; m < 4; ++m)
#pragma unroll
      for (int n = 0; n < 4; ++n)
        acc[m][n] = __builtin_amdgcn_mfma_f32_16x16x32_bf16(af[m], bfr[n], acc[m][n], 0, 0, 0);
    __builtin_amdgcn_s_setprio(0);
    __builtin_amdgcn_sched_barrier(0);
    __builtin_amdgcn_s_barrier();

    // ---------- P1: kk=0, m 4..7; stage t+1 B-K0; mid-tile vmcnt ----------
#pragma unroll
    for (int m = 0; m < 4; ++m)
      af[m] = frag(&As[c][0][0], wm * 128 + 64 + m * 16 + l15, g0);
    if (stage_on) stage_half(Bt, K, bn0, kn, &Bs[nb][0][0], tid);
    __builtin_amdgcn_s_barrier();
    asm volatile("s_waitcnt lgkmcnt(0)" ::: "memory");
    __builtin_amdgcn_sched_barrier(0);
    __builtin_amdgcn_s_setprio(1);
#pragma unroll
    for (int m = 0; m < 4; ++m)
#pragma unroll
      for (int n = 0; n < 4; ++n)
        acc[4 + m][n] = __builtin_amdgcn_mfma_f32_16x16x32_bf16(af[m], bfr[n], acc[4 + m][n], 0, 0, 0);
    __builtin_amdgcn_s_setprio(0);
    __builtin_amdgcn_sched_barrier(0);
    if (!lastt) asm volatile("s_waitcnt vmcnt(4)" ::: "memory");  // t.K1 landed
    else        asm volatile("s_waitcnt vmcnt(0)" ::: "memory");
    __builtin_amdgcn_s_barrier();

    // ---------- P2: kk=1, m 0..3; stage t+1 A-K1 ----------
#pragma unroll
    for (int n = 0; n < 4; ++n)
      bfr[n] = frag(&Bs[c][1][0], wn * 64 + n * 16 + l15, g0);
#pragma unroll
    for (int m = 0; m < 4; ++m)
      af[m] = frag(&As[c][1][0], wm * 128 + m * 16 + l15, g0);
    if (stage_on) stage_half(A, K, bm0, kn + 32, &As[nb][1][0], tid);
    __builtin_amdgcn_s_barrier();
    asm volatile("s_waitcnt lgkmcnt(0)" ::: "memory");
    __builtin_amdgcn_sched_barrier(0);
    __builtin_amdgcn_s_setprio(1);
#pragma unroll
    for (int m = 0; m < 4; ++m)
#pragma unroll
      for (int n = 0; n < 4; ++n)
        acc[m][n] = __builtin_amdgcn_mfma_f32_16x16x32_bf16(af[m], bfr[n], acc[m][n], 0, 0, 0);
    __builtin_amdgcn_s_setprio(0);
    __builtin_amdgcn_sched_barrier(0);
    __builtin_amdgcn_s_barrier();

    // ---------- P3: kk=1, m 4..7; stage t+1 B-K1; boundary vmcnt ----------
#pragma unroll
    for (int m = 0; m < 4; ++m)
      af[m] = frag(&As[c][1][0], wm * 128 + 64 + m * 16 + l15, g0);
    if (stage_on) stage_half(Bt, K, bn0, kn + 32, &Bs[nb][1][0], tid);
    __builtin_amdgcn_s_barrier();
    asm volatile("s_waitcnt lgkmcnt(0)" ::: "memory");
    __builtin_amdgcn_sched_barrier(0);
    __builtin_amdgcn_s_setprio(1);
#pragma unroll
    for (int m = 0; m < 4; ++m)
#pragma unroll
      for (int n = 0; n < 4; ++n)
        acc[4 + m][n] = __builtin_amdgcn_mfma_f32_16x16x32_bf16(af[m], bfr[n], acc[4 + m][n], 0, 0, 0);
    __builtin_amdgcn_s_setprio(0);
    __builtin_amdgcn_sched_barrier(0);
    if (!lastt) asm volatile("s_waitcnt vmcnt(4)" ::: "memory");  // (t+1).K0 landed
    __builtin_amdgcn_s_barrier();
  }

  // epilogue: D row = (ln>>4)*4 + i, col = ln&15 per 16x16 fragment
#pragma unroll
  for (int m = 0; m < 8; ++m) {
    const int r_base = bm0 + wm * 128 + m * 16 + (ln >> 4) * 4;
#pragma unroll
    for (int n = 0; n < 4; ++n) {
      const int cidx = bn0 + wn * 64 + n * 16 + l15;
#pragma unroll
      for (int i = 0; i < 4; ++i) {
        const size_t off = (size_t)(r_base + i) * N + cidx;
        const float v = acc[m][n][i];
        if constexpr (EPI == 0) {
          ((float*)Out)[off] = v;
        } else if constexpr (EPI == 1) {
          ((float*)Out)[off] = Res[off] + v;
        } else if constexpr (EPI == 2) {
          ((u16*)Out)[off] = f2bf(v);
        } else if constexpr (EPI == 3) {
          const float tpos = v > 0.0f ? v : 0.0f;
          ((u16*)Out)[off] = f2bf(tpos * tpos);
        } else {
          ((float*)Out)[off] += v;
        }
      }
    }
  }
}

// ---------------- wkv scan, 3 passes (chunked exp-decay cumsum) ----------------
__global__ __launch_bounds__(256) void k_scan_a(
    const float* __restrict__ kk, const u16* __restrict__ vv,
    const float* __restrict__ td, float* __restrict__ Sloc) {
  const int g = blockIdx.x * 256 + threadIdx.x;   // channel 0..8191
  const int j = blockIdx.y;                       // chunk
  const int ch = g & (C_ - 1);
  const float d = __expf(-__expf(td[ch]));
  const size_t base = ((size_t)(g >> 11) * T_ + (size_t)j * CLEN) * C_ + ch;
  float s = 0.0f;
#pragma unroll 4
  for (int t = 0; t < CLEN; ++t) {
    const size_t idx = base + (size_t)t * C_;
    s = d * s + __expf(kk[idx]) * bf2f(vv[idx]);
  }
  Sloc[(size_t)j * NCHAN + g] = s;
}

__global__ __launch_bounds__(256) void k_scan_b(
    const float* __restrict__ td, const float* __restrict__ Sloc,
    float* __restrict__ carry) {
  const int g = blockIdx.x * 256 + threadIdx.x;
  const int ch = g & (C_ - 1);
  const float dL = __expf(-__expf(td[ch]) * (float)CLEN);
  float s = 0.0f;
#pragma unroll
  for (int j = 0; j < NCH; ++j) {
    carry[(size_t)j * NCHAN + g] = s;
    s = dL * s + Sloc[(size_t)j * NCHAN + g];
  }
}

// pass C: replay with carry, add t=0 bonus, gate with sigmoid(r);
// rwkv may alias rr (in-place): rr[idx] is read before rwkv[idx] is written.
__global__ __launch_bounds__(256) void k_scan_c(
    const float* __restrict__ kk, const u16* __restrict__ vv,
    const u16* __restrict__ rr, const float* __restrict__ td,
    const float* __restrict__ tf, const float* __restrict__ carry,
    u16* __restrict__ rwkv) {
  const int g = blockIdx.x * 256 + threadIdx.x;
  const int j = blockIdx.y;
  const int ch = g & (C_ - 1);
  const float d = __expf(-__expf(td[ch]));
  const float bonus = __expf(tf[ch]);
  const size_t base = ((size_t)(g >> 11) * T_ + (size_t)j * CLEN) * C_ + ch;
  float s = carry[(size_t)j * NCHAN + g];
#pragma unroll 2
  for (int t = 0; t < CLEN; ++t) {
    const size_t idx = base + (size_t)t * C_;
    const float vval = bf2f(vv[idx]);
    s = d * s + __expf(kk[idx]) * vval;
    float wkv = s;
    if (j == 0 && t == 0) wkv += bonus * vval;  // t=0 bonus, output only
    const float rv = bf2f(rr[idx]);
    const float sg = 1.0f / (1.0f + __expf(-rv));
    rwkv[idx] = f2bf(sg * wkv);
  }
}

// ---------------- host launch ----------------
extern "C" void kernel_launch(void* const* d_in, const int* in_sizes, int n_in,
                              void* d_out, int out_size, void* d_ws, size_t ws_size,
                              hipStream_t stream) {
  const float* x    = (const float*)d_in[0];
  const float* td   = (const float*)d_in[1];
  const float* tf   = (const float*)d_in[2];
  const float* Wk   = (const float*)d_in[3];
  const float* Wv   = (const float*)d_in[4];
  const float* Wr   = (const float*)d_in[5];
  const float* Wo   = (const float*)d_in[6];
  const float* Wfk  = (const float*)d_in[7];
  const float* Wfv  = (const float*)d_in[8];
  const float* ln1w = (const float*)d_in[9];
  const float* ln1b = (const float*)d_in[10];
  const float* ln2w = (const float*)d_in[11];
  const float* ln2b = (const float*)d_in[12];
  float* out = (float*)d_out;

  // lean workspace arena (~169 MB), buffers reused aggressively
  char* p = (char*)d_ws;
  auto alloc = [&](size_t bytes) {
    char* r = p;
    p += (bytes + 255) & ~(size_t)255;
    return r;
  };
  u16*   wbuf = (u16*)alloc((size_t)C_ * C_ * 2);    //  8 MB: every transposed weight, serially
  u16*   xl   = (u16*)alloc((size_t)M_ * C_ * 2);    // 32 MB: LN1 out; later FFN hidden chunk
  float* kbuf = (float*)alloc((size_t)M_ * C_ * 4);  // 64 MB: k f32 (dead after scan)
  u16*   vbuf = (u16*)alloc((size_t)M_ * C_ * 2);    // 32 MB: v; later xl2
  u16*   rbuf = (u16*)alloc((size_t)M_ * C_ * 2);    // 32 MB: r; rwkv written in place
  float* Sloc = (float*)alloc((size_t)NCH * NCHAN * 4);
  float* carry = (float*)alloc((size_t)NCH * NCHAN * 4);
  u16* hchunk = xl;   // alias: xl dead after r-projection
  u16* rwkv = rbuf;   // alias: in-place gate (read-before-write per element)

  const dim3 tgrid(C_ / 32, C_ / 32);    // 2048x2048 transpose
  const dim3 ggrid(C_ / 256, M_ / 256);  // 8 x 32 = 256 blocks (1/CU)

  // 1) LN1
  k_layernorm_bf16<<<M_, 256, 0, stream>>>(x, ln1w, ln1b, xl);

  // 2) projections (transpose each weight into wbuf just-in-time; stream-serial)
  k_transpose_cast<<<tgrid, 256, 0, stream>>>(Wk, wbuf, C_, C_, C_);
  k_gemm8<0><<<ggrid, 512, 0, stream>>>(xl, wbuf, kbuf, nullptr, M_, C_, C_);
  k_transpose_cast<<<tgrid, 256, 0, stream>>>(Wv, wbuf, C_, C_, C_);
  k_gemm8<2><<<ggrid, 512, 0, stream>>>(xl, wbuf, vbuf, nullptr, M_, C_, C_);
  k_transpose_cast<<<tgrid, 256, 0, stream>>>(Wr, wbuf, C_, C_, C_);
  k_gemm8<2><<<ggrid, 512, 0, stream>>>(xl, wbuf, rbuf, nullptr, M_, C_, C_);

  // 3) wkv chunked scan + sigmoid gate (rwkv in place of r)
  k_scan_a<<<dim3(NCHAN / 256, NCH), 256, 0, stream>>>(kbuf, vbuf, td, Sloc);
  k_scan_b<<<dim3(NCHAN / 256), 256, 0, stream>>>(td, Sloc, carry);
  k_scan_c<<<dim3(NCHAN / 256, NCH), 256, 0, stream>>>(kbuf, vbuf, rbuf, td, tf, carry, rwkv);

  // 4) x2 = x + rwkv @ Wo  -> straight into d_out
  k_transpose_cast<<<tgrid, 256, 0, stream>>>(Wo, wbuf, C_, C_, C_);
  k_gemm8<1><<<ggrid, 512, 0, stream>>>(rwkv, wbuf, out, x, M_, C_, C_);

  // 5) LN2 (xl2 into vbuf)
  u16* xl2 = vbuf;
  k_layernorm_bf16<<<M_, 256, 0, stream>>>(out, ln2w, ln2b, xl2);

  // 6) FFN chunked over the 4C dimension: out += relu(xl2@Wfk_c)^2 @ Wfv_c
  for (int c = 0; c < 4; ++c) {
    // WfkT chunk: transpose of Wfk[:, c*2048 : (c+1)*2048]  (ld = 4C)
    k_transpose_cast<<<tgrid, 256, 0, stream>>>(Wfk + (size_t)c * C_, wbuf, C4_, C_, C_);
    k_gemm8<3><<<ggrid, 512, 0, stream>>>(xl2, wbuf, hchunk, nullptr, M_, C_, C_);
    // WfvT chunk: transpose of Wfv[c*2048 : (c+1)*2048, :]  (ld = C)
    k_transpose_cast<<<tgrid, 256, 0, stream>>>(Wfv + (size_t)c * C_ * C_, wbuf, C_, C_, C_);
    k_gemm8<4><<<ggrid, 512, 0, stream>>>(hchunk, wbuf, out, nullptr, M_, C_, C_);
  }
}

// Round 4
// 963.178 us; speedup vs baseline: 1.3840x; 1.1947x over previous
//
#include <hip/hip_runtime.h>
#include <hip/hip_bf16.h>
#include <stdint.h>

#define B_  4
#define T_  2048
#define C_  2048
#define H_  32
#define S_  64
#define M_  (B_ * T_)     // 8192 rows
#define C4_ (4 * C_)      // 8192
#define C2_ (2 * C_)      // 4096
#define LN_EPS 1e-5f
#define NCH 16            // scan chunks
#define CLEN 128          // chunk length (NCH*CLEN == T_)
#define NCHAN (B_ * C_)   // 8192 scan channels

typedef unsigned short u16;
typedef __attribute__((ext_vector_type(8))) short short8;
typedef __attribute__((ext_vector_type(4))) float f32x4;

__device__ __forceinline__ u16 f2bf(float f) {
  uint32_t u = __float_as_uint(f);
  u = (u + 0x7FFFu + ((u >> 16) & 1u)) >> 16;
  return (u16)u;
}
__device__ __forceinline__ float bf2f(u16 u) {
  return __uint_as_float(((uint32_t)u) << 16);
}

__device__ __forceinline__ void gload_lds16(const void* g, void* l) {
  __builtin_amdgcn_global_load_lds(
      (const __attribute__((address_space(1))) uint32_t*)g,
      (__attribute__((address_space(3))) uint32_t*)l, 16, 0, 0);
}

// ---- transpose + cast: f32 in[R][Cn] (leading dim ld) -> bf16 out[Cn][R] ----
__global__ __launch_bounds__(256) void k_transpose_cast(
    const float* __restrict__ in, u16* __restrict__ out, int ld, int R, int Cn) {
  __shared__ float tile[32][33];
  const int tx = threadIdx.x & 31, ty = threadIdx.x >> 5; // ty 0..7
  const int c0 = blockIdx.x * 32, r0 = blockIdx.y * 32;
#pragma unroll
  for (int i = 0; i < 4; ++i) {
    int r = ty + i * 8;
    tile[r][tx] = in[(size_t)(r0 + r) * ld + (c0 + tx)];
  }
  __syncthreads();
#pragma unroll
  for (int i = 0; i < 4; ++i) {
    int cc = ty + i * 8;
    out[(size_t)(c0 + cc) * R + (r0 + tx)] = f2bf(tile[tx][cc]);
  }
}

// ---------------- LayerNorm f32 -> bf16, one block per row ----------------
__global__ __launch_bounds__(256) void k_layernorm_bf16(
    const float* __restrict__ x, const float* __restrict__ w,
    const float* __restrict__ bias, u16* __restrict__ out) {
  const int row = blockIdx.x;
  const int t = threadIdx.x;
  const float* xr = x + (size_t)row * C_;
  float4 a = ((const float4*)xr)[2 * t];
  float4 b = ((const float4*)xr)[2 * t + 1];
  float s = a.x + a.y + a.z + a.w + b.x + b.y + b.z + b.w;
  float q = a.x * a.x + a.y * a.y + a.z * a.z + a.w * a.w +
            b.x * b.x + b.y * b.y + b.z * b.z + b.w * b.w;
#pragma unroll
  for (int off = 32; off > 0; off >>= 1) {
    s += __shfl_down(s, off);
    q += __shfl_down(q, off);
  }
  __shared__ float rs[8];
  const int wv = t >> 6;
  if ((t & 63) == 0) { rs[wv] = s; rs[4 + wv] = q; }
  __syncthreads();
  s = rs[0] + rs[1] + rs[2] + rs[3];
  q = rs[4] + rs[5] + rs[6] + rs[7];
  const float mean = s * (1.0f / C_);
  const float rstd = rsqrtf(q * (1.0f / C_) - mean * mean + LN_EPS);
  float4 w0 = ((const float4*)w)[2 * t], w1 = ((const float4*)w)[2 * t + 1];
  float4 b0 = ((const float4*)bias)[2 * t], b1 = ((const float4*)bias)[2 * t + 1];
  uint4 pk;
  pk.x = (uint32_t)f2bf((a.x - mean) * rstd * w0.x + b0.x) |
         ((uint32_t)f2bf((a.y - mean) * rstd * w0.y + b0.y) << 16);
  pk.y = (uint32_t)f2bf((a.z - mean) * rstd * w0.z + b0.z) |
         ((uint32_t)f2bf((a.w - mean) * rstd * w0.w + b0.w) << 16);
  pk.z = (uint32_t)f2bf((b.x - mean) * rstd * w1.x + b1.x) |
         ((uint32_t)f2bf((b.y - mean) * rstd * w1.y + b1.y) << 16);
  pk.w = (uint32_t)f2bf((b.z - mean) * rstd * w1.z + b1.z) |
         ((uint32_t)f2bf((b.w - mean) * rstd * w1.w + b1.w) << 16);
  ((uint4*)(out + (size_t)row * C_))[t] = pk;
}

// ============ GEMM 256x256 tile, BK=64, 8 waves, counted-vmcnt, 2 barriers/K-tile ============
// A[M,K] bf16 row-major, Bt[N,K] bf16 row-major, C = A*Bt^T.
// LDS per matrix: [dbuf 2][K-half 2][256 rows][32 cols] bf16.
// Correctness-required syncs ONLY: per K-half-pair boundary, own-wave
// s_waitcnt vmcnt(4) (never 0 in steady state; T4) + s_barrier to publish
// other waves' staged LDS. No other barriers -> waves drift, so one wave's
// ds_read cluster overlaps another's MFMA cluster (R3 post-mortem: the
// per-phase double-barrier serialized LDS-read time with MFMA time).
// Swizzle: granule slot p of row holds data granule p ^ ((row>>1)&3), applied
// on the global source (linear LDS dest) and on the ds_read address.
// EPI: 0 f32 store | 1 f32 Res+v | 2 bf16 | 3 bf16 relu^2 | 4 f32 Out+=v
__device__ __forceinline__ void stage_half(
    const u16* __restrict__ G, int ldK, int row0, int kcol0,
    u16* lds_half, int tid) {
#pragma unroll
  for (int i = 0; i < 2; ++i) {
    const int slot = i * 512 + tid;
    const int row = slot >> 2;
    const int gs = slot & 3;
    const int gsrc = gs ^ ((row >> 1) & 3);
    gload_lds16(G + (size_t)(row0 + row) * ldK + kcol0 + gsrc * 8,
                ((char*)lds_half) + i * 8192 + (tid >> 6) * 1024);
  }
}

__device__ __forceinline__ short8 frag(const u16* half_base, int row, int g0) {
  const int g = g0 ^ ((row >> 1) & 3);
  return *(const short8*)(half_base + row * 32 + g * 8);
}

template <int EPI>
__global__ __launch_bounds__(512, 2) void k_gemm8(
    const u16* __restrict__ A, const u16* __restrict__ Bt,
    void* __restrict__ Out, const float* __restrict__ Res,
    int M, int N, int K) {
  __shared__ u16 As[2][2][256 * 32];   // 64 KB
  __shared__ u16 Bs[2][2][256 * 32];   // 64 KB
  const int tid = threadIdx.x;
  const int wv = tid >> 6, ln = tid & 63;
  const int wm = wv >> 2, wn = wv & 3;          // 2 x 4 wave grid
  const int l15 = ln & 15, g0 = ln >> 4;

  // XCD-aware remap (T1): linear id % 8 = XCD; give each XCD a contiguous
  // band of by (shared A-panels L2-resident). Bijective since nwg % 8 == 0.
  const int lin = blockIdx.y * gridDim.x + blockIdx.x;
  const int xcd = lin & 7, slot = lin >> 3;
  const int bx = slot % gridDim.x;
  const int by = xcd * (gridDim.y >> 3) + slot / gridDim.x;
  const int bm0 = by * 256, bn0 = bx * 256;
  const int NT = K >> 6;

  f32x4 acc[8][4];
#pragma unroll
  for (int m = 0; m < 8; ++m)
#pragma unroll
    for (int n = 0; n < 4; ++n) acc[m][n] = (f32x4)0.0f;

  // prologue: stage tile 0 fully (A-K0, B-K0, A-K1, B-K1) = 8 loads/thread
  stage_half(A, K, bm0, 0, &As[0][0][0], tid);
  stage_half(Bt, K, bn0, 0, &Bs[0][0][0], tid);
  stage_half(A, K, bm0, 32, &As[0][1][0], tid);
  stage_half(Bt, K, bn0, 32, &Bs[0][1][0], tid);
  asm volatile("s_waitcnt vmcnt(4)" ::: "memory");   // K0 halves landed
  __builtin_amdgcn_s_barrier();

  for (int t = 0; t < NT; ++t) {
    const int c = t & 1, nb = c ^ 1;
    const int kn = (t + 1) << 6;
    const bool stage_on = (t + 1 < NT);
    const bool lastt = (t + 1 == NT);
    short8 bfr[4], af[4];

#pragma unroll
    for (int h = 0; h < 2; ++h) {
      // -- sub-phase A: quadrant m0..3 of K-half h; stage t+1 A-half h --
#pragma unroll
      for (int n = 0; n < 4; ++n)
        bfr[n] = frag(&Bs[c][h][0], wn * 64 + n * 16 + l15, g0);
#pragma unroll
      for (int m = 0; m < 4; ++m)
        af[m] = frag(&As[c][h][0], wm * 128 + m * 16 + l15, g0);
      if (stage_on) stage_half(A, K, bm0, kn + h * 32, &As[nb][h][0], tid);
      asm volatile("s_waitcnt lgkmcnt(0)" ::: "memory");
      __builtin_amdgcn_sched_barrier(0);
      __builtin_amdgcn_s_setprio(1);
#pragma unroll
      for (int m = 0; m < 4; ++m)
#pragma unroll
        for (int n = 0; n < 4; ++n)
          acc[m][n] = __builtin_amdgcn_mfma_f32_16x16x32_bf16(af[m], bfr[n], acc[m][n], 0, 0, 0);
      __builtin_amdgcn_s_setprio(0);

      // -- sub-phase B: quadrant m4..7 of K-half h; stage t+1 B-half h --
#pragma unroll
      for (int m = 0; m < 4; ++m)
        af[m] = frag(&As[c][h][0], wm * 128 + 64 + m * 16 + l15, g0);
      if (stage_on) stage_half(Bt, K, bn0, kn + h * 32, &Bs[nb][h][0], tid);
      asm volatile("s_waitcnt lgkmcnt(0)" ::: "memory");
      __builtin_amdgcn_sched_barrier(0);
      __builtin_amdgcn_s_setprio(1);
#pragma unroll
      for (int m = 0; m < 4; ++m)
#pragma unroll
        for (int n = 0; n < 4; ++n)
          acc[4 + m][n] = __builtin_amdgcn_mfma_f32_16x16x32_bf16(af[m], bfr[n], acc[4 + m][n], 0, 0, 0);
      __builtin_amdgcn_s_setprio(0);

      // -- K-half boundary: publish staged half (counted vmcnt, never 0 mid-loop) --
      if (h == 0) {
        if (!lastt) asm volatile("s_waitcnt vmcnt(4)" ::: "memory");  // t.K1 landed
        else        asm volatile("s_waitcnt vmcnt(0)" ::: "memory");
        __builtin_amdgcn_s_barrier();
      } else if (!lastt) {
        asm volatile("s_waitcnt vmcnt(4)" ::: "memory");              // (t+1).K0 landed
        __builtin_amdgcn_s_barrier();
      }
    }
  }

  // epilogue: D row = (ln>>4)*4 + i, col = ln&15 per 16x16 fragment
#pragma unroll
  for (int m = 0; m < 8; ++m) {
    const int r_base = bm0 + wm * 128 + m * 16 + (ln >> 4) * 4;
#pragma unroll
    for (int n = 0; n < 4; ++n) {
      const int cidx = bn0 + wn * 64 + n * 16 + l15;
#pragma unroll
      for (int i = 0; i < 4; ++i) {
        const size_t off = (size_t)(r_base + i) * N + cidx;
        const float v = acc[m][n][i];
        if constexpr (EPI == 0) {
          ((float*)Out)[off] = v;
        } else if constexpr (EPI == 1) {
          ((float*)Out)[off] = Res[off] + v;
        } else if constexpr (EPI == 2) {
          ((u16*)Out)[off] = f2bf(v);
        } else if constexpr (EPI == 3) {
          const float tpos = v > 0.0f ? v : 0.0f;
          ((u16*)Out)[off] = f2bf(tpos * tpos);
        } else {
          ((float*)Out)[off] += v;
        }
      }
    }
  }
}

// ---------------- wkv scan, 3 passes (chunked exp-decay cumsum) ----------------
__global__ __launch_bounds__(256) void k_scan_a(
    const float* __restrict__ kk, const u16* __restrict__ vv,
    const float* __restrict__ td, float* __restrict__ Sloc) {
  const int g = blockIdx.x * 256 + threadIdx.x;   // channel 0..8191
  const int j = blockIdx.y;                       // chunk
  const int ch = g & (C_ - 1);
  const float d = __expf(-__expf(td[ch]));
  const size_t base = ((size_t)(g >> 11) * T_ + (size_t)j * CLEN) * C_ + ch;
  float s = 0.0f;
#pragma unroll 4
  for (int t = 0; t < CLEN; ++t) {
    const size_t idx = base + (size_t)t * C_;
    s = d * s + __expf(kk[idx]) * bf2f(vv[idx]);
  }
  Sloc[(size_t)j * NCHAN + g] = s;
}

__global__ __launch_bounds__(256) void k_scan_b(
    const float* __restrict__ td, const float* __restrict__ Sloc,
    float* __restrict__ carry) {
  const int g = blockIdx.x * 256 + threadIdx.x;
  const int ch = g & (C_ - 1);
  const float dL = __expf(-__expf(td[ch]) * (float)CLEN);
  float s = 0.0f;
#pragma unroll
  for (int j = 0; j < NCH; ++j) {
    carry[(size_t)j * NCHAN + g] = s;
    s = dL * s + Sloc[(size_t)j * NCHAN + g];
  }
}

// pass C: replay with carry, add t=0 bonus, gate with sigmoid(r);
// rwkv may alias rr (in-place): rr[idx] is read before rwkv[idx] is written.
__global__ __launch_bounds__(256) void k_scan_c(
    const float* __restrict__ kk, const u16* __restrict__ vv,
    const u16* __restrict__ rr, const float* __restrict__ td,
    const float* __restrict__ tf, const float* __restrict__ carry,
    u16* __restrict__ rwkv) {
  const int g = blockIdx.x * 256 + threadIdx.x;
  const int j = blockIdx.y;
  const int ch = g & (C_ - 1);
  const float d = __expf(-__expf(td[ch]));
  const float bonus = __expf(tf[ch]);
  const size_t base = ((size_t)(g >> 11) * T_ + (size_t)j * CLEN) * C_ + ch;
  float s = carry[(size_t)j * NCHAN + g];
#pragma unroll 2
  for (int t = 0; t < CLEN; ++t) {
    const size_t idx = base + (size_t)t * C_;
    const float vval = bf2f(vv[idx]);
    s = d * s + __expf(kk[idx]) * vval;
    float wkv = s;
    if (j == 0 && t == 0) wkv += bonus * vval;  // t=0 bonus, output only
    const float rv = bf2f(rr[idx]);
    const float sg = 1.0f / (1.0f + __expf(-rv));
    rwkv[idx] = f2bf(sg * wkv);
  }
}

// ---------------- host launch ----------------
extern "C" void kernel_launch(void* const* d_in, const int* in_sizes, int n_in,
                              void* d_out, int out_size, void* d_ws, size_t ws_size,
                              hipStream_t stream) {
  const float* x    = (const float*)d_in[0];
  const float* td   = (const float*)d_in[1];
  const float* tf   = (const float*)d_in[2];
  const float* Wk   = (const float*)d_in[3];
  const float* Wv   = (const float*)d_in[4];
  const float* Wr   = (const float*)d_in[5];
  const float* Wo   = (const float*)d_in[6];
  const float* Wfk  = (const float*)d_in[7];
  const float* Wfv  = (const float*)d_in[8];
  const float* ln1w = (const float*)d_in[9];
  const float* ln1b = (const float*)d_in[10];
  const float* ln2w = (const float*)d_in[11];
  const float* ln2b = (const float*)d_in[12];
  float* out = (float*)d_out;

  // lean workspace arena (~169 MB, proven in R2), buffers reused aggressively
  char* p = (char*)d_ws;
  auto alloc = [&](size_t bytes) {
    char* r = p;
    p += (bytes + 255) & ~(size_t)255;
    return r;
  };
  u16*   wbuf = (u16*)alloc((size_t)C_ * C_ * 2);    //  8 MB: square transposed weights
  u16*   xl   = (u16*)alloc((size_t)M_ * C_ * 2);    // 32 MB: LN1 out; later FFN hidden (w/ kbuf)
  float* kbuf = (float*)alloc((size_t)M_ * C_ * 4);  // 64 MB: k f32 (dead after scan)
  u16*   vbuf = (u16*)alloc((size_t)M_ * C_ * 2);    // 32 MB: v; later xl2
  u16*   rbuf = (u16*)alloc((size_t)M_ * C_ * 2);    // 32 MB: r / rwkv; later FFN chunk weights
  float* Sloc = (float*)alloc((size_t)NCH * NCHAN * 4);
  float* carry = (float*)alloc((size_t)NCH * NCHAN * 4);
  u16* rwkv = rbuf;     // alias: in-place gate (read-before-write per element)
  u16* hchunk = xl;     // alias: 64 MB spanning xl+kbuf (both dead in FFN stage)
  u16* wfbuf = rbuf;    // alias: 16 MB FFN chunk weight (rwkv dead after Wo GEMM)

  const dim3 tgrid(C_ / 32, C_ / 32);    // 2048x2048 transpose
  const dim3 ggrid(C_ / 256, M_ / 256);  // 8 x 32 = 256 blocks (1/CU)

  // 1) LN1
  k_layernorm_bf16<<<M_, 256, 0, stream>>>(x, ln1w, ln1b, xl);

  // 2) projections (transpose each weight into wbuf just-in-time; stream-serial)
  k_transpose_cast<<<tgrid, 256, 0, stream>>>(Wk, wbuf, C_, C_, C_);
  k_gemm8<0><<<ggrid, 512, 0, stream>>>(xl, wbuf, kbuf, nullptr, M_, C_, C_);
  k_transpose_cast<<<tgrid, 256, 0, stream>>>(Wv, wbuf, C_, C_, C_);
  k_gemm8<2><<<ggrid, 512, 0, stream>>>(xl, wbuf, vbuf, nullptr, M_, C_, C_);
  k_transpose_cast<<<tgrid, 256, 0, stream>>>(Wr, wbuf, C_, C_, C_);
  k_gemm8<2><<<ggrid, 512, 0, stream>>>(xl, wbuf, rbuf, nullptr, M_, C_, C_);

  // 3) wkv chunked scan + sigmoid gate (rwkv in place of r)
  k_scan_a<<<dim3(NCHAN / 256, NCH), 256, 0, stream>>>(kbuf, vbuf, td, Sloc);
  k_scan_b<<<dim3(NCHAN / 256), 256, 0, stream>>>(td, Sloc, carry);
  k_scan_c<<<dim3(NCHAN / 256, NCH), 256, 0, stream>>>(kbuf, vbuf, rbuf, td, tf, carry, rwkv);

  // 4) x2 = x + rwkv @ Wo  -> straight into d_out
  k_transpose_cast<<<tgrid, 256, 0, stream>>>(Wo, wbuf, C_, C_, C_);
  k_gemm8<1><<<ggrid, 512, 0, stream>>>(rwkv, wbuf, out, x, M_, C_, C_);

  // 5) LN2 (xl2 into vbuf)
  u16* xl2 = vbuf;
  k_layernorm_bf16<<<M_, 256, 0, stream>>>(out, ln2w, ln2b, xl2);

  // 6) FFN in 2 chunks of 4096: out += relu(xl2@Wfk_c)^2 @ Wfv_c
  for (int c = 0; c < 2; ++c) {
    // WfkT chunk: transpose of Wfk[:, c*4096 : (c+1)*4096]  (ld = 4C) -> [4096][2048]
    k_transpose_cast<<<dim3(C2_ / 32, C_ / 32), 256, 0, stream>>>(
        Wfk + (size_t)c * C2_, wfbuf, C4_, C_, C2_);
    k_gemm8<3><<<dim3(C2_ / 256, M_ / 256), 512, 0, stream>>>(
        xl2, wfbuf, hchunk, nullptr, M_, C2_, C_);
    // WfvT chunk: transpose of Wfv[c*4096 : (c+1)*4096, :]  (ld = C) -> [2048][4096]
    k_transpose_cast<<<dim3(C_ / 32, C2_ / 32), 256, 0, stream>>>(
        Wfv + (size_t)c * C2_ * C_, wfbuf, C_, C2_, C_);
    k_gemm8<4><<<dim3(C_ / 256, M_ / 256), 512, 0, stream>>>(
        hchunk, wfbuf, out, nullptr, M_, C_, C2_);
  }
}

// Round 5
// 955.604 us; speedup vs baseline: 1.3950x; 1.0079x over previous
//
#include <hip/hip_runtime.h>
#include <hip/hip_bf16.h>
#include <stdint.h>

#define B_  4
#define T_  2048
#define C_  2048
#define H_  32
#define S_  64
#define M_  (B_ * T_)     // 8192 rows
#define C4_ (4 * C_)      // 8192
#define C2_ (2 * C_)      // 4096
#define LN_EPS 1e-5f
#define NCH 16            // scan chunks
#define CLEN 128          // chunk length (NCH*CLEN == T_)
#define NCHAN (B_ * C_)   // 8192 scan channels

typedef unsigned short u16;
typedef __attribute__((ext_vector_type(8))) short short8;
typedef __attribute__((ext_vector_type(4))) float f32x4;

__device__ __forceinline__ u16 f2bf(float f) {
  uint32_t u = __float_as_uint(f);
  u = (u + 0x7FFFu + ((u >> 16) & 1u)) >> 16;
  return (u16)u;
}
__device__ __forceinline__ float bf2f(u16 u) {
  return __uint_as_float(((uint32_t)u) << 16);
}

__device__ __forceinline__ void gload_lds16(const void* g, void* l) {
  __builtin_amdgcn_global_load_lds(
      (const __attribute__((address_space(1))) uint32_t*)g,
      (__attribute__((address_space(3))) uint32_t*)l, 16, 0, 0);
}

// ---- transpose + cast: f32 in[R][Cn] (leading dim ld) -> bf16 out[Cn][R] ----
__global__ __launch_bounds__(256) void k_transpose_cast(
    const float* __restrict__ in, u16* __restrict__ out, int ld, int R, int Cn) {
  __shared__ float tile[32][33];
  const int tx = threadIdx.x & 31, ty = threadIdx.x >> 5; // ty 0..7
  const int c0 = blockIdx.x * 32, r0 = blockIdx.y * 32;
#pragma unroll
  for (int i = 0; i < 4; ++i) {
    int r = ty + i * 8;
    tile[r][tx] = in[(size_t)(r0 + r) * ld + (c0 + tx)];
  }
  __syncthreads();
#pragma unroll
  for (int i = 0; i < 4; ++i) {
    int cc = ty + i * 8;
    out[(size_t)(c0 + cc) * R + (r0 + tx)] = f2bf(tile[tx][cc]);
  }
}

// ---------------- LayerNorm f32 -> bf16, one block per row ----------------
__global__ __launch_bounds__(256) void k_layernorm_bf16(
    const float* __restrict__ x, const float* __restrict__ w,
    const float* __restrict__ bias, u16* __restrict__ out) {
  const int row = blockIdx.x;
  const int t = threadIdx.x;
  const float* xr = x + (size_t)row * C_;
  float4 a = ((const float4*)xr)[2 * t];
  float4 b = ((const float4*)xr)[2 * t + 1];
  float s = a.x + a.y + a.z + a.w + b.x + b.y + b.z + b.w;
  float q = a.x * a.x + a.y * a.y + a.z * a.z + a.w * a.w +
            b.x * b.x + b.y * b.y + b.z * b.z + b.w * b.w;
#pragma unroll
  for (int off = 32; off > 0; off >>= 1) {
    s += __shfl_down(s, off);
    q += __shfl_down(q, off);
  }
  __shared__ float rs[8];
  const int wv = t >> 6;
  if ((t & 63) == 0) { rs[wv] = s; rs[4 + wv] = q; }
  __syncthreads();
  s = rs[0] + rs[1] + rs[2] + rs[3];
  q = rs[4] + rs[5] + rs[6] + rs[7];
  const float mean = s * (1.0f / C_);
  const float rstd = rsqrtf(q * (1.0f / C_) - mean * mean + LN_EPS);
  float4 w0 = ((const float4*)w)[2 * t], w1 = ((const float4*)w)[2 * t + 1];
  float4 b0 = ((const float4*)bias)[2 * t], b1 = ((const float4*)bias)[2 * t + 1];
  uint4 pk;
  pk.x = (uint32_t)f2bf((a.x - mean) * rstd * w0.x + b0.x) |
         ((uint32_t)f2bf((a.y - mean) * rstd * w0.y + b0.y) << 16);
  pk.y = (uint32_t)f2bf((a.z - mean) * rstd * w0.z + b0.z) |
         ((uint32_t)f2bf((a.w - mean) * rstd * w0.w + b0.w) << 16);
  pk.z = (uint32_t)f2bf((b.x - mean) * rstd * w1.x + b1.x) |
         ((uint32_t)f2bf((b.y - mean) * rstd * w1.y + b1.y) << 16);
  pk.w = (uint32_t)f2bf((b.z - mean) * rstd * w1.z + b1.z) |
         ((uint32_t)f2bf((b.w - mean) * rstd * w1.w + b1.w) << 16);
  ((uint4*)(out + (size_t)row * C_))[t] = pk;
}

// ============ GEMM 256x256 tile, BK=64, 8 waves, counted-vmcnt, 2 barriers/K-tile ============
// A[M,K] bf16 row-major, Bt[N,K] bf16 row-major, C = A*Bt^T.
// LDS per matrix: [dbuf 2][K-half 2][256 rows][32 cols] bf16.
// Correctness rails ONLY: per K-half boundary, own-wave s_waitcnt vmcnt(4)
// (never 0 in steady state; T4) + s_barrier (publish other waves' staged LDS)
// + sched_barrier(0) (compile-time pin: no ds_read hoists above the barrier).
// NO lgkmcnt(0)/sched_barrier/setprio inside the compute clusters (R4 post-
// mortem: forcing a full LDS drain before each MFMA cluster serialized the
// ~270cy LDS round-trip against the 77cy MFMA cluster; the compiler's native
// fine-grained lgkmcnt(4/3/1/0) interleave pipelines LDS latency into MFMA).
// Swizzle: granule slot p of row holds data granule p ^ ((row>>1)&3), applied
// on the global source (linear LDS dest) and on the ds_read address.
// EPI: 0 f32 store | 1 f32 Res+v | 2 bf16 | 3 bf16 relu^2 | 4 f32 Out+=v
__device__ __forceinline__ void stage_half(
    const u16* __restrict__ G, int ldK, int row0, int kcol0,
    u16* lds_half, int tid) {
#pragma unroll
  for (int i = 0; i < 2; ++i) {
    const int slot = i * 512 + tid;
    const int row = slot >> 2;
    const int gs = slot & 3;
    const int gsrc = gs ^ ((row >> 1) & 3);
    gload_lds16(G + (size_t)(row0 + row) * ldK + kcol0 + gsrc * 8,
                ((char*)lds_half) + i * 8192 + (tid >> 6) * 1024);
  }
}

__device__ __forceinline__ short8 frag(const u16* half_base, int row, int g0) {
  const int g = g0 ^ ((row >> 1) & 3);
  return *(const short8*)(half_base + row * 32 + g * 8);
}

template <int EPI>
__global__ __launch_bounds__(512, 2) void k_gemm8(
    const u16* __restrict__ A, const u16* __restrict__ Bt,
    void* __restrict__ Out, const float* __restrict__ Res,
    int M, int N, int K) {
  __shared__ u16 As[2][2][256 * 32];   // 64 KB
  __shared__ u16 Bs[2][2][256 * 32];   // 64 KB
  const int tid = threadIdx.x;
  const int wv = tid >> 6, ln = tid & 63;
  const int wm = wv >> 2, wn = wv & 3;          // 2 x 4 wave grid
  const int l15 = ln & 15, g0 = ln >> 4;

  // XCD-aware remap (T1): linear id % 8 = XCD; give each XCD a contiguous
  // band of by (shared A-panels L2-resident). Bijective since nwg % 8 == 0.
  const int lin = blockIdx.y * gridDim.x + blockIdx.x;
  const int xcd = lin & 7, slot = lin >> 3;
  const int bx = slot % gridDim.x;
  const int by = xcd * (gridDim.y >> 3) + slot / gridDim.x;
  const int bm0 = by * 256, bn0 = bx * 256;
  const int NT = K >> 6;

  f32x4 acc[8][4];
#pragma unroll
  for (int m = 0; m < 8; ++m)
#pragma unroll
    for (int n = 0; n < 4; ++n) acc[m][n] = (f32x4)0.0f;

  // prologue: stage tile 0 fully (A-K0, B-K0, A-K1, B-K1) = 8 loads/thread
  stage_half(A, K, bm0, 0, &As[0][0][0], tid);
  stage_half(Bt, K, bn0, 0, &Bs[0][0][0], tid);
  stage_half(A, K, bm0, 32, &As[0][1][0], tid);
  stage_half(Bt, K, bn0, 32, &Bs[0][1][0], tid);
  asm volatile("s_waitcnt vmcnt(4)" ::: "memory");   // K0 halves landed
  __builtin_amdgcn_s_barrier();
  __builtin_amdgcn_sched_barrier(0);

  for (int t = 0; t < NT; ++t) {
    const int c = t & 1, nb = c ^ 1;
    const int kn = (t + 1) << 6;
    const bool stage_on = (t + 1 < NT);
    const bool lastt = (t + 1 == NT);
    short8 bfr[4], af[4];

#pragma unroll
    for (int h = 0; h < 2; ++h) {
      // -- sub-phase A: quadrant m0..3 of K-half h; stage t+1 A-half h --
#pragma unroll
      for (int n = 0; n < 4; ++n)
        bfr[n] = frag(&Bs[c][h][0], wn * 64 + n * 16 + l15, g0);
#pragma unroll
      for (int m = 0; m < 4; ++m)
        af[m] = frag(&As[c][h][0], wm * 128 + m * 16 + l15, g0);
      if (stage_on) stage_half(A, K, bm0, kn + h * 32, &As[nb][h][0], tid);
#pragma unroll
      for (int m = 0; m < 4; ++m)
#pragma unroll
        for (int n = 0; n < 4; ++n)
          acc[m][n] = __builtin_amdgcn_mfma_f32_16x16x32_bf16(af[m], bfr[n], acc[m][n], 0, 0, 0);

      // -- sub-phase B: quadrant m4..7 of K-half h; stage t+1 B-half h --
#pragma unroll
      for (int m = 0; m < 4; ++m)
        af[m] = frag(&As[c][h][0], wm * 128 + 64 + m * 16 + l15, g0);
      if (stage_on) stage_half(Bt, K, bn0, kn + h * 32, &Bs[nb][h][0], tid);
#pragma unroll
      for (int m = 0; m < 4; ++m)
#pragma unroll
        for (int n = 0; n < 4; ++n)
          acc[4 + m][n] = __builtin_amdgcn_mfma_f32_16x16x32_bf16(af[m], bfr[n], acc[4 + m][n], 0, 0, 0);

      // -- K-half boundary: publish staged half (counted vmcnt, never 0 mid-loop) --
      if (h == 0) {
        if (!lastt) asm volatile("s_waitcnt vmcnt(4)" ::: "memory");  // t.K1 landed
        else        asm volatile("s_waitcnt vmcnt(0)" ::: "memory");
        __builtin_amdgcn_s_barrier();
        __builtin_amdgcn_sched_barrier(0);
      } else if (!lastt) {
        asm volatile("s_waitcnt vmcnt(4)" ::: "memory");              // (t+1).K0 landed
        __builtin_amdgcn_s_barrier();
        __builtin_amdgcn_sched_barrier(0);
      }
    }
  }

  // epilogue: D row = (ln>>4)*4 + i, col = ln&15 per 16x16 fragment
#pragma unroll
  for (int m = 0; m < 8; ++m) {
    const int r_base = bm0 + wm * 128 + m * 16 + (ln >> 4) * 4;
#pragma unroll
    for (int n = 0; n < 4; ++n) {
      const int cidx = bn0 + wn * 64 + n * 16 + l15;
#pragma unroll
      for (int i = 0; i < 4; ++i) {
        const size_t off = (size_t)(r_base + i) * N + cidx;
        const float v = acc[m][n][i];
        if constexpr (EPI == 0) {
          ((float*)Out)[off] = v;
        } else if constexpr (EPI == 1) {
          ((float*)Out)[off] = Res[off] + v;
        } else if constexpr (EPI == 2) {
          ((u16*)Out)[off] = f2bf(v);
        } else if constexpr (EPI == 3) {
          const float tpos = v > 0.0f ? v : 0.0f;
          ((u16*)Out)[off] = f2bf(tpos * tpos);
        } else {
          ((float*)Out)[off] += v;
        }
      }
    }
  }
}

// ---------------- wkv scan, 3 passes (chunked exp-decay cumsum) ----------------
__global__ __launch_bounds__(256) void k_scan_a(
    const float* __restrict__ kk, const u16* __restrict__ vv,
    const float* __restrict__ td, float* __restrict__ Sloc) {
  const int g = blockIdx.x * 256 + threadIdx.x;   // channel 0..8191
  const int j = blockIdx.y;                       // chunk
  const int ch = g & (C_ - 1);
  const float d = __expf(-__expf(td[ch]));
  const size_t base = ((size_t)(g >> 11) * T_ + (size_t)j * CLEN) * C_ + ch;
  float s = 0.0f;
#pragma unroll 4
  for (int t = 0; t < CLEN; ++t) {
    const size_t idx = base + (size_t)t * C_;
    s = d * s + __expf(kk[idx]) * bf2f(vv[idx]);
  }
  Sloc[(size_t)j * NCHAN + g] = s;
}

__global__ __launch_bounds__(256) void k_scan_b(
    const float* __restrict__ td, const float* __restrict__ Sloc,
    float* __restrict__ carry) {
  const int g = blockIdx.x * 256 + threadIdx.x;
  const int ch = g & (C_ - 1);
  const float dL = __expf(-__expf(td[ch]) * (float)CLEN);
  float s = 0.0f;
#pragma unroll
  for (int j = 0; j < NCH; ++j) {
    carry[(size_t)j * NCHAN + g] = s;
    s = dL * s + Sloc[(size_t)j * NCHAN + g];
  }
}

// pass C: replay with carry, add t=0 bonus, gate with sigmoid(r);
// rwkv may alias rr (in-place): rr[idx] is read before rwkv[idx] is written.
__global__ __launch_bounds__(256) void k_scan_c(
    const float* __restrict__ kk, const u16* __restrict__ vv,
    const u16* __restrict__ rr, const float* __restrict__ td,
    const float* __restrict__ tf, const float* __restrict__ carry,
    u16* __restrict__ rwkv) {
  const int g = blockIdx.x * 256 + threadIdx.x;
  const int j = blockIdx.y;
  const int ch = g & (C_ - 1);
  const float d = __expf(-__expf(td[ch]));
  const float bonus = __expf(tf[ch]);
  const size_t base = ((size_t)(g >> 11) * T_ + (size_t)j * CLEN) * C_ + ch;
  float s = carry[(size_t)j * NCHAN + g];
#pragma unroll 2
  for (int t = 0; t < CLEN; ++t) {
    const size_t idx = base + (size_t)t * C_;
    const float vval = bf2f(vv[idx]);
    s = d * s + __expf(kk[idx]) * vval;
    float wkv = s;
    if (j == 0 && t == 0) wkv += bonus * vval;  // t=0 bonus, output only
    const float rv = bf2f(rr[idx]);
    const float sg = 1.0f / (1.0f + __expf(-rv));
    rwkv[idx] = f2bf(sg * wkv);
  }
}

// ---------------- host launch ----------------
extern "C" void kernel_launch(void* const* d_in, const int* in_sizes, int n_in,
                              void* d_out, int out_size, void* d_ws, size_t ws_size,
                              hipStream_t stream) {
  const float* x    = (const float*)d_in[0];
  const float* td   = (const float*)d_in[1];
  const float* tf   = (const float*)d_in[2];
  const float* Wk   = (const float*)d_in[3];
  const float* Wv   = (const float*)d_in[4];
  const float* Wr   = (const float*)d_in[5];
  const float* Wo   = (const float*)d_in[6];
  const float* Wfk  = (const float*)d_in[7];
  const float* Wfv  = (const float*)d_in[8];
  const float* ln1w = (const float*)d_in[9];
  const float* ln1b = (const float*)d_in[10];
  const float* ln2w = (const float*)d_in[11];
  const float* ln2b = (const float*)d_in[12];
  float* out = (float*)d_out;

  // lean workspace arena (~169 MB, proven in R2), buffers reused aggressively
  char* p = (char*)d_ws;
  auto alloc = [&](size_t bytes) {
    char* r = p;
    p += (bytes + 255) & ~(size_t)255;
    return r;
  };
  u16*   wbuf = (u16*)alloc((size_t)C_ * C_ * 2);    //  8 MB: square transposed weights
  u16*   xl   = (u16*)alloc((size_t)M_ * C_ * 2);    // 32 MB: LN1 out; later FFN hidden (w/ kbuf)
  float* kbuf = (float*)alloc((size_t)M_ * C_ * 4);  // 64 MB: k f32 (dead after scan)
  u16*   vbuf = (u16*)alloc((size_t)M_ * C_ * 2);    // 32 MB: v; later xl2
  u16*   rbuf = (u16*)alloc((size_t)M_ * C_ * 2);    // 32 MB: r / rwkv; later FFN chunk weights
  float* Sloc = (float*)alloc((size_t)NCH * NCHAN * 4);
  float* carry = (float*)alloc((size_t)NCH * NCHAN * 4);
  u16* rwkv = rbuf;     // alias: in-place gate (read-before-write per element)
  u16* hchunk = xl;     // alias: 64 MB spanning xl+kbuf (both dead in FFN stage)
  u16* wfbuf = rbuf;    // alias: 16 MB FFN chunk weight (rwkv dead after Wo GEMM)

  const dim3 tgrid(C_ / 32, C_ / 32);    // 2048x2048 transpose
  const dim3 ggrid(C_ / 256, M_ / 256);  // 8 x 32 = 256 blocks (1/CU)

  // 1) LN1
  k_layernorm_bf16<<<M_, 256, 0, stream>>>(x, ln1w, ln1b, xl);

  // 2) projections (transpose each weight into wbuf just-in-time; stream-serial)
  k_transpose_cast<<<tgrid, 256, 0, stream>>>(Wk, wbuf, C_, C_, C_);
  k_gemm8<0><<<ggrid, 512, 0, stream>>>(xl, wbuf, kbuf, nullptr, M_, C_, C_);
  k_transpose_cast<<<tgrid, 256, 0, stream>>>(Wv, wbuf, C_, C_, C_);
  k_gemm8<2><<<ggrid, 512, 0, stream>>>(xl, wbuf, vbuf, nullptr, M_, C_, C_);
  k_transpose_cast<<<tgrid, 256, 0, stream>>>(Wr, wbuf, C_, C_, C_);
  k_gemm8<2><<<ggrid, 512, 0, stream>>>(xl, wbuf, rbuf, nullptr, M_, C_, C_);

  // 3) wkv chunked scan + sigmoid gate (rwkv in place of r)
  k_scan_a<<<dim3(NCHAN / 256, NCH), 256, 0, stream>>>(kbuf, vbuf, td, Sloc);
  k_scan_b<<<dim3(NCHAN / 256), 256, 0, stream>>>(td, Sloc, carry);
  k_scan_c<<<dim3(NCHAN / 256, NCH), 256, 0, stream>>>(kbuf, vbuf, rbuf, td, tf, carry, rwkv);

  // 4) x2 = x + rwkv @ Wo  -> straight into d_out
  k_transpose_cast<<<tgrid, 256, 0, stream>>>(Wo, wbuf, C_, C_, C_);
  k_gemm8<1><<<ggrid, 512, 0, stream>>>(rwkv, wbuf, out, x, M_, C_, C_);

  // 5) LN2 (xl2 into vbuf)
  u16* xl2 = vbuf;
  k_layernorm_bf16<<<M_, 256, 0, stream>>>(out, ln2w, ln2b, xl2);

  // 6) FFN in 2 chunks of 4096: out += relu(xl2@Wfk_c)^2 @ Wfv_c
  for (int c = 0; c < 2; ++c) {
    // WfkT chunk: transpose of Wfk[:, c*4096 : (c+1)*4096]  (ld = 4C) -> [4096][2048]
    k_transpose_cast<<<dim3(C2_ / 32, C_ / 32), 256, 0, stream>>>(
        Wfk + (size_t)c * C2_, wfbuf, C4_, C_, C2_);
    k_gemm8<3><<<dim3(C2_ / 256, M_ / 256), 512, 0, stream>>>(
        xl2, wfbuf, hchunk, nullptr, M_, C2_, C_);
    // WfvT chunk: transpose of Wfv[c*4096 : (c+1)*4096, :]  (ld = C) -> [2048][4096]
    k_transpose_cast<<<dim3(C_ / 32, C2_ / 32), 256, 0, stream>>>(
        Wfv + (size_t)c * C2_ * C_, wfbuf, C_, C2_, C_);
    k_gemm8<4><<<dim3(C_ / 256, M_ / 256), 512, 0, stream>>>(
        hchunk, wfbuf, out, nullptr, M_, C_, C2_);
  }
}